// Round 7
// baseline (313.719 us; speedup 1.0000x reference)
//
#include <hip/hip_runtime.h>

#define BATCH   4
#define SEQLEN  4096
#define NHEADS  32
#define PDIM    64
#define NDIM    16
#define CHUNK   64
#define NCHUNK  64   // SEQLEN / CHUNK
#define PHALF   32

typedef short v8s __attribute__((ext_vector_type(8)));
typedef float v4f __attribute__((ext_vector_type(4)));

union V8U { v8s s; unsigned u[4]; };

__device__ __forceinline__ short f2bf(float f) {
    union { float f; unsigned u; } x; x.f = f;
    unsigned r = (x.u + 0x7FFFu + ((x.u >> 16) & 1u)) >> 16;  // RNE
    return (short)r;
}
__device__ __forceinline__ float bf2f(short s) {
    union { unsigned u; float f; } x; x.u = ((unsigned)(unsigned short)s) << 16;
    return x.f;
}
// HW packed f32->bf16 (RNE), 2 elems/inst.
__device__ __forceinline__ unsigned cvt_pk_bf16(float lo, float hi) {
    unsigned r;
    asm("v_cvt_pk_bf16_f32 %0, %1, %2" : "=v"(r) : "v"(lo), "v"(hi));
    return r;
}

__device__ __forceinline__ float wave_iscan(float v, int lane) {
#pragma unroll
    for (int d = 1; d < 64; d <<= 1) {
        float o = __shfl_up(v, (unsigned)d, 64);
        if (lane >= d) v += o;
    }
    return v;
}

// ---------------------------------------------------------------------------
// Fused SSD kernel v8: producer-side state scan, one uniform slot per chunk.
// Grid (2 p-halves, NHEADS, BATCH) = 256 blocks, 8 waves.
// Slot k (one converged barrier at the end):
//   producers (waves 4-7): stage(k+2); waves 4-5 also run the chunk-k state
//     MFMAs (staged data only), update running S in producer registers, and
//     publish sF[(k+1)&3] for slot k+1's Y_off.  The serial scan thus lives
//     entirely OFF the consumer critical path.
//   consumers (waves 0-3): full chunk k — own-strip QK^T -> G (same-wave:
//     wave W writes/reads only gRaw rows [16W,16W+16), no cross-wave G, no
//     mid-barrier, single gRaw buffer) -> Y_diag + Y_off (sF[k&3], published
//     one slot earlier).
// Whole-sequence A-cumsum precomputed once in sCumAll (verified r4/r6).
// Quad-buffered frag LDS: slot k reads buf k&3, stages (k+2)&3 — disjoint.
// ---------------------------------------------------------------------------
__global__ __launch_bounds__(512) void k_fused(
    const float* __restrict__ X, const float* __restrict__ A,
    const float* __restrict__ Bm, const float* __restrict__ Cm,
    float* __restrict__ Y)
{
    const int ph = blockIdx.x, hh = blockIdx.y, bb = blockIdx.z;
    const int tid = threadIdx.x;
    const int lane = tid & 63;
    const int wv = tid >> 6;           // 0..7
    const int W = wv & 3;
    const int qq = lane >> 4, nn = lane & 15;

    __shared__ __align__(16) float sCumAll[SEQLEN];   // 16 KB
    __shared__ __align__(16) short xF [4][4][64][8];  // 16 KB
    __shared__ __align__(16) short xSF[4][4][64][8];  // 16 KB
    __shared__ __align__(16) short cFq[4][2048];      // 16 KB (K=n zero-pad)
    __shared__ __align__(16) short bFq[4][2048];      // 16 KB
    __shared__ __align__(16) short bFs[4][1024];      // 8 KB
    __shared__ __align__(16) short sF [4][1024];      // 8 KB
    __shared__ __align__(16) float gRaw[CHUNK][68];   // 17.4 KB (single buffer)
    __shared__ float wtot[8];
    // total ~114 KB -> 1 block/CU (grid == 256 == #CUs)

    {   // zero-init qk-frag pad regions (all 4 bufs) + sF[0] (S_prev=0)
        const v8s z8 = {0,0,0,0,0,0,0,0};
        ((v8s*)cFq)[tid] = z8; ((v8s*)cFq)[tid + 512] = z8;
        ((v8s*)bFq)[tid] = z8; ((v8s*)bFq)[tid + 512] = z8;
        if (tid < 128) ((v8s*)sF)[tid] = z8;
    }

    // ---- whole-sequence A cumsum (one-time, all 8 waves) ----
    {
        const float* Ab = A + (size_t)bb * SEQLEN * NHEADS + hh;
        const int tb = wv * 512 + lane * 8;
        float av[8];
#pragma unroll
        for (int j = 0; j < 8; ++j) av[j] = Ab[(size_t)(tb + j) * NHEADS];
        float s8 = 0.f;
#pragma unroll
        for (int j = 0; j < 8; ++j) s8 += av[j];
        const float pre = wave_iscan(s8, lane);
        if (lane == 63) wtot[wv] = pre;
        __syncthreads();
        float base = 0.f;
#pragma unroll
        for (int w = 0; w < 7; ++w) if (w < wv) base += wtot[w];
        float c = base + pre - s8;             // exclusive prefix of this lane
#pragma unroll
        for (int j = 0; j < 8; ++j) { c += av[j]; sCumAll[tb + j] = c; }
        __syncthreads();
    }

    auto stage = [&](int c, int buf) {
        const int t0c = bb * SEQLEN + c * CHUNK;
        const float* gcc = &sCumAll[c * CHUNK];
        // X tile per producer wave (kk, nt), transposed load -> xF + xSF
        const int ti = wv - 4, kk = ti >> 1, nt = ti & 1;
        const int trow = kk * 32 + qq * 8;
        const float* xb = X + ((size_t)(t0c + trow) * NHEADS + hh) * PDIM
                            + ph * PHALF + nt * 16 + nn;
        float xv[8];
#pragma unroll
        for (int j = 0; j < 8; ++j) xv[j] = xb[(size_t)j * (NHEADS * PDIM)];
        const float gtot = gcc[63];
        float ex[8];
#pragma unroll
        for (int j = 0; j < 8; ++j) ex[j] = __expf(gtot - gcc[trow + j]);
        V8U xf, xs;
#pragma unroll
        for (int j2 = 0; j2 < 4; ++j2) {
            xf.u[j2] = cvt_pk_bf16(xv[2*j2], xv[2*j2+1]);
            xs.u[j2] = cvt_pk_bf16(xv[2*j2] * ex[2*j2], xv[2*j2+1] * ex[2*j2+1]);
        }
        *(v8s*)&xF [buf][kk*2+nt][lane][0] = xf.s;
        *(v8s*)&xSF[buf][kk*2+nt][lane][0] = xs.s;
        // B (both frag layouts) + C over the 256 producer threads
        const int ptid = tid & 255;
        const int r = ptid >> 2, n0 = (ptid & 3) * 4;
        const float4 bv = *(const float4*)&Bm[((size_t)(t0c + r) * NHEADS + hh) * NDIM + n0];
        const int offq = ((r >> 4) * 64 + (n0 >> 3) * 16 + (r & 15)) * 8 + (n0 & 7);
        bFq[buf][offq + 0] = f2bf(bv.x); bFq[buf][offq + 1] = f2bf(bv.y);
        bFq[buf][offq + 2] = f2bf(bv.z); bFq[buf][offq + 3] = f2bf(bv.w);
        const int kb = r >> 5, qb = (r >> 3) & 3, jj = r & 7;
        const int bs = (kb * 64 + qb * 16) * 8 + jj;
        bFs[buf][bs + (n0 + 0) * 8] = f2bf(bv.x);
        bFs[buf][bs + (n0 + 1) * 8] = f2bf(bv.y);
        bFs[buf][bs + (n0 + 2) * 8] = f2bf(bv.z);
        bFs[buf][bs + (n0 + 3) * 8] = f2bf(bv.w);
        const float4 cv = *(const float4*)&Cm[((size_t)(t0c + r) * NHEADS + hh) * NDIM + n0];
        cFq[buf][offq + 0] = f2bf(cv.x); cFq[buf][offq + 1] = f2bf(cv.y);
        cFq[buf][offq + 2] = f2bf(cv.z); cFq[buf][offq + 3] = f2bf(cv.w);
    };

    const v4f zero = {0.f, 0.f, 0.f, 0.f};

    // QK^T -> G rows for this wave's own strip W (mask st <= W); same-wave.
    auto qk_g = [&](const float* gc, int buf) -> v8s {
        const v8s cfrag = *(const v8s*)&cFq[buf][(W * 64 + lane) * 8];
        float tc[4];
#pragma unroll
        for (int r = 0; r < 4; ++r) tc[r] = gc[W * 16 + qq * 4 + r];
#pragma unroll
        for (int st = 0; st < 4; ++st) {
            if (st <= W) {
                const v8s bfrag = *(const v8s*)&bFq[buf][(st * 64 + lane) * 8];
                v4f acc = __builtin_amdgcn_mfma_f32_16x16x32_bf16(cfrag, bfrag, zero, 0, 0, 0);
                const float cums = gc[st * 16 + nn];
#pragma unroll
                for (int r = 0; r < 4; ++r) {
                    const int t = W * 16 + qq * 4 + r;
                    const int s = st * 16 + nn;
                    gRaw[t][s] = (t >= s) ? acc[r] * __expf(tc[r] - cums) : 0.f;
                }
            }
        }
        if (W == 0) {
#pragma unroll
            for (int r = 0; r < 4; ++r) gRaw[qq * 4 + r][16 + nn] = 0.f;
        } else if (W == 2) {
#pragma unroll
            for (int r = 0; r < 4; ++r) gRaw[32 + qq * 4 + r][48 + nn] = 0.f;
        }
        return cfrag;
    };

    // Y for this wave's strip W of chunk at t0c (G in gRaw, same-wave rows)
    auto do_y = [&](const float* gc, float gbase, int buf, int t0c, v8s cfrag) {
        const float et = __expf(gc[W * 16 + nn] - gbase);
        V8U cef;
#pragma unroll
        for (int j2 = 0; j2 < 4; ++j2)
            cef.u[j2] = cvt_pk_bf16(bf2f(cfrag[2*j2]) * et, bf2f(cfrag[2*j2+1]) * et);
        V8U ga0u, ga1u;
        {
            const float* gr = &gRaw[W * 16 + nn][qq * 8];          // kk=0
#pragma unroll
            for (int j2 = 0; j2 < 4; ++j2) ga0u.u[j2] = cvt_pk_bf16(gr[2*j2], gr[2*j2+1]);
        }
        const bool usekk1 = (W >= 2);
        if (usekk1) {
            const float* gr = &gRaw[W * 16 + nn][32 + qq * 8];     // kk=1
#pragma unroll
            for (int j2 = 0; j2 < 4; ++j2) ga1u.u[j2] = cvt_pk_bf16(gr[2*j2], gr[2*j2+1]);
        }
        v4f ya[2];
#pragma unroll
        for (int nt2 = 0; nt2 < 2; ++nt2) {
            const v8s sfrag = *(const v8s*)&sF[buf][(nt2 * 64 + lane) * 8];
            v4f a = __builtin_amdgcn_mfma_f32_16x16x32_bf16(cef.s, sfrag, zero, 0, 0, 0);
            const v8s x0 = *(const v8s*)&xF[buf][0 + nt2][lane][0];
            a = __builtin_amdgcn_mfma_f32_16x16x32_bf16(ga0u.s, x0, a, 0, 0, 0);
            if (usekk1) {
                const v8s x1 = *(const v8s*)&xF[buf][2 + nt2][lane][0];
                a = __builtin_amdgcn_mfma_f32_16x16x32_bf16(ga1u.s, x1, a, 0, 0, 0);
            }
            ya[nt2] = a;
        }
#pragma unroll
        for (int r = 0; r < 4; ++r) {
            const int t = W * 16 + qq * 4 + r;
            float* yp = Y + ((size_t)(t0c + t) * NHEADS + hh) * PDIM + ph * PHALF + nn;
            yp[0]  = ya[0][r];
            yp[16] = ya[1][r];
        }
    };

    if (wv >= 4) { stage(0, 0); stage(1, 1); }
    __syncthreads();

    v4f S = {0.f, 0.f, 0.f, 0.f};     // running scanned state (producer waves 4-5)

#pragma unroll 1
    for (int k = 0; k < NCHUNK; ++k) {
        const int buf = k & 3;
        const float* gc = &sCumAll[k * CHUNK];
        const float gbase = (k == 0) ? 0.f : gc[-1];

        if (wv >= 4) {
            if (k + 2 < NCHUNK) stage(k + 2, (k + 2) & 3);
            if (wv < 6) {
                // chunk-k state update (producer-side scan), Wp = p-tile id
                const int Wp = wv - 4;
                const v8s a0 = *(const v8s*)&xSF[buf][0 + Wp][lane][0];
                const v8s a1 = *(const v8s*)&xSF[buf][2 + Wp][lane][0];
                const v8s b0 = *(const v8s*)&bFs[buf][(0 * 64 + lane) * 8];
                const v8s b1 = *(const v8s*)&bFs[buf][(1 * 64 + lane) * 8];
                v4f sa = __builtin_amdgcn_mfma_f32_16x16x32_bf16(a0, b0, zero, 0, 0, 0);
                sa = __builtin_amdgcn_mfma_f32_16x16x32_bf16(a1, b1, sa, 0, 0, 0);
                const float Et = __expf(gc[63] - gbase);
#pragma unroll
                for (int r = 0; r < 4; ++r) S[r] = Et * S[r] + sa[r];
                short* d = &sF[(k + 1) & 3][0];      // S(k), consumed at slot k+1
#pragma unroll
                for (int r = 0; r < 4; ++r)
                    d[(Wp * 64 + (nn >> 3) * 16 + qq * 4 + r) * 8 + (nn & 7)] = f2bf(S[r]);
            }
        } else {
            __builtin_amdgcn_s_setprio(1);
            const int t0c = bb * SEQLEN + k * CHUNK;
            const v8s cfrag = qk_g(gc, buf);
            do_y(gc, gbase, buf, t0c, cfrag);
            __builtin_amdgcn_s_setprio(0);
        }
        __syncthreads();               // converged
    }
}

// ---------------------------------------------------------------------------
extern "C" void kernel_launch(void* const* d_in, const int* in_sizes, int n_in,
                              void* d_out, int out_size, void* d_ws, size_t ws_size,
                              hipStream_t stream) {
    const float* X  = (const float*)d_in[0];
    const float* A  = (const float*)d_in[1];
    const float* Bm = (const float*)d_in[2];
    const float* Cm = (const float*)d_in[3];
    float* Y = (float*)d_out;
    (void)d_ws; (void)ws_size;

    dim3 grid(2, NHEADS, BATCH);
    k_fused<<<grid, 512, 0, stream>>>(X, A, Bm, Cm, Y);
}

// Round 8
// 299.918 us; speedup vs baseline: 1.0460x; 1.0460x over previous
//
#include <hip/hip_runtime.h>

#define BATCH   4
#define SEQLEN  4096
#define NHEADS  32
#define PDIM    64
#define NDIM    16
#define CHUNK   64
#define NCHUNK  64   // SEQLEN / CHUNK
#define PHALF   32

typedef short v8s __attribute__((ext_vector_type(8)));
typedef float v4f __attribute__((ext_vector_type(4)));

union V8U { v8s s; unsigned u[4]; };

__device__ __forceinline__ short f2bf(float f) {
    union { float f; unsigned u; } x; x.f = f;
    unsigned r = (x.u + 0x7FFFu + ((x.u >> 16) & 1u)) >> 16;  // RNE
    return (short)r;
}
__device__ __forceinline__ float bf2f(short s) {
    union { unsigned u; float f; } x; x.u = ((unsigned)(unsigned short)s) << 16;
    return x.f;
}
// HW packed f32->bf16 (RNE), 2 elems/inst.
__device__ __forceinline__ unsigned cvt_pk_bf16(float lo, float hi) {
    unsigned r;
    asm("v_cvt_pk_bf16_f32 %0, %1, %2" : "=v"(r) : "v"(lo), "v"(hi));
    return r;
}

__device__ __forceinline__ float wave_iscan(float v, int lane) {
#pragma unroll
    for (int d = 1; d < 64; d <<= 1) {
        float o = __shfl_up(v, (unsigned)d, 64);
        if (lane >= d) v += o;
    }
    return v;
}

// ---------------------------------------------------------------------------
// Fused SSD kernel v9 = v8 + T14/T4: staged loads split issue-early/write-late,
// loop barrier = lgkmcnt(0) + raw s_barrier (NO vmcnt drain — global loads
// stay in flight across slots; Y stores never drained in-loop).
// Grid (2 p-halves, NHEADS, BATCH) = 256 blocks, 8 waves.
// Slot k:
//   producers (4-7): writec(k+2) from regs loaded in slot k-1; issue
//     loadc(k+3); waves 4-5 run chunk-k state MFMAs + serial S (producer-side
//     scan) and publish sF[(k+1)&3].
//   consumers (0-3): own-strip QK^T -> G (same-wave gRaw rows) -> Y.
//   tail (converged): s_waitcnt lgkmcnt(0); s_barrier.
// Whole-sequence A-cumsum in sCumAll (verified r4/r6/r7).
// ---------------------------------------------------------------------------
__global__ __launch_bounds__(512) void k_fused(
    const float* __restrict__ X, const float* __restrict__ A,
    const float* __restrict__ Bm, const float* __restrict__ Cm,
    float* __restrict__ Y)
{
    const int ph = blockIdx.x, hh = blockIdx.y, bb = blockIdx.z;
    const int tid = threadIdx.x;
    const int lane = tid & 63;
    const int wv = tid >> 6;           // 0..7
    const int W = wv & 3;
    const int qq = lane >> 4, nn = lane & 15;

    __shared__ __align__(16) float sCumAll[SEQLEN];   // 16 KB
    __shared__ __align__(16) short xF [4][4][64][8];  // 16 KB
    __shared__ __align__(16) short xSF[4][4][64][8];  // 16 KB
    __shared__ __align__(16) short cFq[4][2048];      // 16 KB (K=n zero-pad)
    __shared__ __align__(16) short bFq[4][2048];      // 16 KB
    __shared__ __align__(16) short bFs[4][1024];      // 8 KB
    __shared__ __align__(16) short sF [4][1024];      // 8 KB
    __shared__ __align__(16) float gRaw[CHUNK][68];   // 17.4 KB
    __shared__ float wtot[8];
    // total ~114 KB -> 1 block/CU

    {   // zero-init qk-frag pad regions (all 4 bufs) + sF[0] (S_prev=0)
        const v8s z8 = {0,0,0,0,0,0,0,0};
        ((v8s*)cFq)[tid] = z8; ((v8s*)cFq)[tid + 512] = z8;
        ((v8s*)bFq)[tid] = z8; ((v8s*)bFq)[tid + 512] = z8;
        if (tid < 128) ((v8s*)sF)[tid] = z8;
    }

    // ---- whole-sequence A cumsum (one-time, all 8 waves) ----
    {
        const float* Ab = A + (size_t)bb * SEQLEN * NHEADS + hh;
        const int tb = wv * 512 + lane * 8;
        float av[8];
#pragma unroll
        for (int j = 0; j < 8; ++j) av[j] = Ab[(size_t)(tb + j) * NHEADS];
        float s8 = 0.f;
#pragma unroll
        for (int j = 0; j < 8; ++j) s8 += av[j];
        const float pre = wave_iscan(s8, lane);
        if (lane == 63) wtot[wv] = pre;
        __syncthreads();
        float base = 0.f;
#pragma unroll
        for (int w = 0; w < 7; ++w) if (w < wv) base += wtot[w];
        float c = base + pre - s8;             // exclusive prefix of this lane
#pragma unroll
        for (int j = 0; j < 8; ++j) { c += av[j]; sCumAll[tb + j] = c; }
        __syncthreads();
    }

    // ---- producer in-flight registers (T14 issue-early / write-late) ----
    float pxv[8];
    float4 pbv, pcv;

    // issue global loads for chunk c into registers (no wait here)
    auto loadc = [&](int c) {
        const int t0c = bb * SEQLEN + c * CHUNK;
        const int ti = wv - 4, kk = ti >> 1, nt = ti & 1;
        const int trow = kk * 32 + qq * 8;
        const float* xb = X + ((size_t)(t0c + trow) * NHEADS + hh) * PDIM
                            + ph * PHALF + nt * 16 + nn;
#pragma unroll
        for (int j = 0; j < 8; ++j) pxv[j] = xb[(size_t)j * (NHEADS * PDIM)];
        const int ptid = tid & 255;
        const int r = ptid >> 2, n0 = (ptid & 3) * 4;
        pbv = *(const float4*)&Bm[((size_t)(t0c + r) * NHEADS + hh) * NDIM + n0];
        pcv = *(const float4*)&Cm[((size_t)(t0c + r) * NHEADS + hh) * NDIM + n0];
    };

    // pack registers of chunk c into LDS frag buffers
    auto writec = [&](int c, int buf) {
        const float* gcc = &sCumAll[c * CHUNK];
        const int ti = wv - 4, kk = ti >> 1, nt = ti & 1;
        const int trow = kk * 32 + qq * 8;
        const float gtot = gcc[63];
        float ex[8];
#pragma unroll
        for (int j = 0; j < 8; ++j) ex[j] = __expf(gtot - gcc[trow + j]);
        V8U xf, xs;
#pragma unroll
        for (int j2 = 0; j2 < 4; ++j2) {
            xf.u[j2] = cvt_pk_bf16(pxv[2*j2], pxv[2*j2+1]);
            xs.u[j2] = cvt_pk_bf16(pxv[2*j2] * ex[2*j2], pxv[2*j2+1] * ex[2*j2+1]);
        }
        *(v8s*)&xF [buf][kk*2+nt][lane][0] = xf.s;
        *(v8s*)&xSF[buf][kk*2+nt][lane][0] = xs.s;
        const int ptid = tid & 255;
        const int r = ptid >> 2, n0 = (ptid & 3) * 4;
        const int offq = ((r >> 4) * 64 + (n0 >> 3) * 16 + (r & 15)) * 8 + (n0 & 7);
        const unsigned b01 = cvt_pk_bf16(pbv.x, pbv.y), b23 = cvt_pk_bf16(pbv.z, pbv.w);
        const unsigned c01 = cvt_pk_bf16(pcv.x, pcv.y), c23 = cvt_pk_bf16(pcv.z, pcv.w);
        uint2 bq; bq.x = b01; bq.y = b23;
        uint2 cq; cq.x = c01; cq.y = c23;
        *(uint2*)&bFq[buf][offq] = bq;         // offq*2 bytes is 8B-aligned
        *(uint2*)&cFq[buf][offq] = cq;
        const int kb = r >> 5, qb = (r >> 3) & 3, jj = r & 7;
        const int bs = (kb * 64 + qb * 16) * 8 + jj;
        bFs[buf][bs + (n0 + 0) * 8] = (short)(b01 & 0xFFFF);
        bFs[buf][bs + (n0 + 1) * 8] = (short)(b01 >> 16);
        bFs[buf][bs + (n0 + 2) * 8] = (short)(b23 & 0xFFFF);
        bFs[buf][bs + (n0 + 3) * 8] = (short)(b23 >> 16);
    };

    const v4f zero = {0.f, 0.f, 0.f, 0.f};

    // QK^T -> G rows, own strip W (mask st <= W); factored exp (8 transcends)
    auto qk_g = [&](const float* gc, float gbase, int buf) -> v8s {
        const v8s cfrag = *(const v8s*)&cFq[buf][(W * 64 + lane) * 8];
        float er[4];
#pragma unroll
        for (int r = 0; r < 4; ++r) er[r] = __expf(gc[W * 16 + qq * 4 + r] - gbase);
#pragma unroll
        for (int st = 0; st < 4; ++st) {
            if (st <= W) {
                const v8s bfrag = *(const v8s*)&bFq[buf][(st * 64 + lane) * 8];
                v4f acc = __builtin_amdgcn_mfma_f32_16x16x32_bf16(cfrag, bfrag, zero, 0, 0, 0);
                const float ec = __expf(gbase - gc[st * 16 + nn]);
#pragma unroll
                for (int r = 0; r < 4; ++r) {
                    const int t = W * 16 + qq * 4 + r;
                    const int s = st * 16 + nn;
                    gRaw[t][s] = (t >= s) ? acc[r] * er[r] * ec : 0.f;
                }
            }
        }
        if (W == 0) {
#pragma unroll
            for (int r = 0; r < 4; ++r) gRaw[qq * 4 + r][16 + nn] = 0.f;
        } else if (W == 2) {
#pragma unroll
            for (int r = 0; r < 4; ++r) gRaw[32 + qq * 4 + r][48 + nn] = 0.f;
        }
        return cfrag;
    };

    // Y for strip W of chunk at t0c (G in gRaw, same-wave rows)
    auto do_y = [&](const float* gc, float gbase, int buf, int t0c, v8s cfrag) {
        const float et = __expf(gc[W * 16 + nn] - gbase);
        V8U cef;
#pragma unroll
        for (int j2 = 0; j2 < 4; ++j2)
            cef.u[j2] = cvt_pk_bf16(bf2f(cfrag[2*j2]) * et, bf2f(cfrag[2*j2+1]) * et);
        V8U ga0u, ga1u;
        {
            const float* gr = &gRaw[W * 16 + nn][qq * 8];          // kk=0
#pragma unroll
            for (int j2 = 0; j2 < 4; ++j2) ga0u.u[j2] = cvt_pk_bf16(gr[2*j2], gr[2*j2+1]);
        }
        const bool usekk1 = (W >= 2);
        if (usekk1) {
            const float* gr = &gRaw[W * 16 + nn][32 + qq * 8];     // kk=1
#pragma unroll
            for (int j2 = 0; j2 < 4; ++j2) ga1u.u[j2] = cvt_pk_bf16(gr[2*j2], gr[2*j2+1]);
        }
        v4f ya[2];
#pragma unroll
        for (int nt2 = 0; nt2 < 2; ++nt2) {
            const v8s sfrag = *(const v8s*)&sF[buf][(nt2 * 64 + lane) * 8];
            v4f a = __builtin_amdgcn_mfma_f32_16x16x32_bf16(cef.s, sfrag, zero, 0, 0, 0);
            const v8s x0 = *(const v8s*)&xF[buf][0 + nt2][lane][0];
            a = __builtin_amdgcn_mfma_f32_16x16x32_bf16(ga0u.s, x0, a, 0, 0, 0);
            if (usekk1) {
                const v8s x1 = *(const v8s*)&xF[buf][2 + nt2][lane][0];
                a = __builtin_amdgcn_mfma_f32_16x16x32_bf16(ga1u.s, x1, a, 0, 0, 0);
            }
            ya[nt2] = a;
        }
#pragma unroll
        for (int r = 0; r < 4; ++r) {
            const int t = W * 16 + qq * 4 + r;
            float* yp = Y + ((size_t)(t0c + t) * NHEADS + hh) * PDIM + ph * PHALF + nn;
            yp[0]  = ya[0][r];
            yp[16] = ya[1][r];
        }
    };

    // ---- prologue: chunks 0,1 staged; chunk 2 loads in flight ----
    if (wv >= 4) {
        loadc(0); writec(0, 0);
        loadc(1); writec(1, 1);
        loadc(2);
    }
    __syncthreads();    // full drain once (also lands loadc(2) regs)

    v4f S = {0.f, 0.f, 0.f, 0.f};     // running scanned state (producer waves 4-5)

#pragma unroll 1
    for (int k = 0; k < NCHUNK; ++k) {
        const int buf = k & 3;
        const float* gc = &sCumAll[k * CHUNK];
        const float gbase = (k == 0) ? 0.f : gc[-1];

        if (wv >= 4) {
            if (k + 2 < NCHUNK) writec(k + 2, (k + 2) & 3);  // regs from slot k-1
            if (k + 3 < NCHUNK) loadc(k + 3);                // in flight across barrier
            if (wv < 6) {
                // chunk-k state update (producer-side scan), Wp = p-tile id
                const int Wp = wv - 4;
                const v8s a0 = *(const v8s*)&xSF[buf][0 + Wp][lane][0];
                const v8s a1 = *(const v8s*)&xSF[buf][2 + Wp][lane][0];
                const v8s b0 = *(const v8s*)&bFs[buf][(0 * 64 + lane) * 8];
                const v8s b1 = *(const v8s*)&bFs[buf][(1 * 64 + lane) * 8];
                v4f sa = __builtin_amdgcn_mfma_f32_16x16x32_bf16(a0, b0, zero, 0, 0, 0);
                sa = __builtin_amdgcn_mfma_f32_16x16x32_bf16(a1, b1, sa, 0, 0, 0);
                const float Et = __expf(gc[63] - gbase);
#pragma unroll
                for (int r = 0; r < 4; ++r) S[r] = Et * S[r] + sa[r];
                short* d = &sF[(k + 1) & 3][0];      // S(k), consumed at slot k+1
#pragma unroll
                for (int r = 0; r < 4; ++r)
                    d[(Wp * 64 + (nn >> 3) * 16 + qq * 4 + r) * 8 + (nn & 7)] = f2bf(S[r]);
            }
        } else {
            __builtin_amdgcn_s_setprio(1);
            const int t0c = bb * SEQLEN + k * CHUNK;
            const v8s cfrag = qk_g(gc, gbase, buf);
            do_y(gc, gbase, buf, t0c, cfrag);
            __builtin_amdgcn_s_setprio(0);
        }

        // converged slot boundary: publish LDS, do NOT drain vmcnt
        asm volatile("s_waitcnt lgkmcnt(0)" ::: "memory");
        __builtin_amdgcn_s_barrier();
        asm volatile("" ::: "memory");
    }
}

// ---------------------------------------------------------------------------
extern "C" void kernel_launch(void* const* d_in, const int* in_sizes, int n_in,
                              void* d_out, int out_size, void* d_ws, size_t ws_size,
                              hipStream_t stream) {
    const float* X  = (const float*)d_in[0];
    const float* A  = (const float*)d_in[1];
    const float* Bm = (const float*)d_in[2];
    const float* Cm = (const float*)d_in[3];
    float* Y = (float*)d_out;
    (void)d_ws; (void)ws_size;

    dim3 grid(2, NHEADS, BATCH);
    k_fused<<<grid, 512, 0, stream>>>(X, A, Bm, Cm, Y);
}